// Round 15
// baseline (2174.518 us; speedup 1.0000x reference)
//
#include <hip/hip_runtime.h>
#include <hip/hip_bf16.h>

#define N_SENT 2048
#define S_LEN  64
#define QL     16
#define NQ     128
#define NB     32
#define DD     256
#define VOCAB  100032

#define PADC 264        // A row length (ushort), 528B = 16B-aligned rows

using bf16x8 = __attribute__((ext_vector_type(8))) short;
using f32x4  = __attribute__((ext_vector_type(4))) float;

// ---------------- workspace layout (float offsets) ----------------
#define WS_X    0
#define WS_WX   (WS_X  + N_SENT*DD)
#define WS_Q    (WS_WX + N_SENT*DD)
#define WS_KS   (WS_Q  + NQ*DD)
#define WS_KVB  (WS_KS + N_SENT*NB)
#define WS_HF   (WS_KVB+ NB*DD)
#define WS_Z    (WS_HF + NB*DD)
#define WS_BF   (WS_Z  + NQ*DD)       // 65536 ushort = 32768 float slots

// ---------------- encoders ----------------
__global__ __launch_bounds__(256) void encode_story(
    const int* __restrict__ inp, const float* __restrict__ emb,
    const float* __restrict__ f, float* __restrict__ X)
{
    const int t = blockIdx.x, d = threadIdx.x;
    __shared__ int idx[S_LEN];
    if (d < S_LEN) idx[d] = inp[t*S_LEN + d];
    __syncthreads();
    float acc = 0.f;
#pragma unroll 4
    for (int p = 0; p < S_LEN; ++p)
        acc += emb[(size_t)idx[p]*DD + d] * f[p*DD + d];
    X[t*DD + d] = acc;
}

__global__ __launch_bounds__(256) void encode_query(
    const int* __restrict__ qry, const float* __restrict__ emb,
    const float* __restrict__ f, float* __restrict__ Q)
{
    const int i = blockIdx.x, d = threadIdx.x;
    __shared__ int idx[QL];
    if (d < QL) idx[d] = qry[i*QL + d];
    __syncthreads();
    float acc = 0.f;
#pragma unroll
    for (int p = 0; p < QL; ++p)
        acc += emb[(size_t)idx[p]*DD + d] * f[p*DD + d];
    Q[i*DD + d] = acc;
}

// ---------------- WX / KS ----------------
__global__ __launch_bounds__(256) void wx_ks(
    const float* __restrict__ X, const float* __restrict__ W,
    const float* __restrict__ keys, float* __restrict__ WX, float* __restrict__ KS)
{
    const int t = blockIdx.x, n = threadIdx.x;
    __shared__ float xs[DD];
    xs[n] = X[t*DD + n];
    __syncthreads();
    float acc = 0.f;
    const float4* wr = (const float4*)&W[n*DD];
    const float4* xp = (const float4*)xs;
#pragma unroll 8
    for (int k4 = 0; k4 < 64; ++k4) {
        float4 w = wr[k4], x = xp[k4];
        acc += w.x*x.x + w.y*x.y + w.z*x.z + w.w*x.w;
    }
    WX[t*DD + n] = acc;
    if (n < NB) {
        float a2 = 0.f;
        const float4* kr = (const float4*)&keys[n*DD];
#pragma unroll 8
        for (int k4 = 0; k4 < 64; ++k4) {
            float4 kv = kr[k4], x = xp[k4];
            a2 += kv.x*x.x + kv.y*x.y + kv.z*x.z + kv.w*x.w;
        }
        KS[t*NB + n] = a2;
    }
}

// ---------------- KVB ----------------
__global__ __launch_bounds__(256) void kvb_kernel(
    const float* __restrict__ keys, const float* __restrict__ V,
    const float* __restrict__ bias, float* __restrict__ KVB)
{
    const int jj = blockIdx.x, n = threadIdx.x;
    __shared__ float ks[DD];
    ks[n] = keys[jj*DD + n];
    __syncthreads();
    float acc = bias[n];
    const float4* vr = (const float4*)&V[n*DD];
    const float4* kp = (const float4*)ks;
#pragma unroll 8
    for (int k4 = 0; k4 < 64; ++k4) {
        float4 v = vr[k4], k = kp[k4];
        acc += v.x*k.x + v.y*k.y + v.z*k.z + v.w*k.w;
    }
    KVB[jj*DD + n] = acc;
}

// ---------------- prep: U -> RNE bf16 MFMA B-fragments (single pass) ----------------
__global__ __launch_bounds__(64) void prep_ufrag(
    const float* __restrict__ U, ushort* __restrict__ Bf)
{
    const int f = blockIdx.x;         // 0..127
    const int l = threadIdx.x;        // 0..63
    const int kt = f & 7, nt = f >> 3;
    const int n  = nt*16 + (l & 15);
    const int kb = kt*32 + (l >> 4)*8;
    ushort out[8];
#pragma unroll
    for (int i = 0; i < 8; ++i) {
        __hip_bfloat16 b = __float2bfloat16(U[n*DD + kb + i]);  // RNE
        out[i] = *reinterpret_cast<ushort*>(&b);
    }
    *(uint4*)&Bf[((size_t)f*64 + l)*8] = *(const uint4*)out;
}

__device__ __forceinline__ void split_hilo(float v, ushort& hi, ushort& lo)
{
    unsigned b = __float_as_uint(v);
    unsigned h = b & 0xFFFF0000u;
    hi = (ushort)(h >> 16);
    lo = (ushort)(__float_as_uint(v - __uint_as_float(h)) >> 16);
}

template <int CTRL>
__device__ __forceinline__ int dpp_i(int v) {
    return __builtin_amdgcn_update_dpp(0, v, CTRL, 0xF, 0xF, true);
}
template <int CTRL>
__device__ __forceinline__ float dpp_f(float x) {
    return __int_as_float(dpp_i<CTRL>(__float_as_int(x)));
}

__device__ __forceinline__ float red16(float x) {   // sum over 16-lane row
    x += dpp_f<0xB1>(x);
    x += dpp_f<0x4E>(x);
    x += dpp_f<0x141>(x);
    x += dpp_f<0x140>(x);
    return x;
}
__device__ __forceinline__ float red4(float x) {    // sum over 4-lane group
    x += dpp_f<0xB1>(x);
    x += dpp_f<0x4E>(x);
    return x;
}

// Component select on compile-time tau (post-unroll constant).
#define CSEL(V, TAU) ((TAU)==0 ? (V).x : (TAU)==1 ? (V).y : (TAU)==2 ? (V).z : (V).w)

// One scan step, 4-wave version. Wave w owns N-tiles 4w..4w+3 (dims
// [64w,64w+64)). 32 MFMAs/wave as 8 independent 4-deep chains. pred has 4
// entries (one per wave) -> red4. Barrier syncs 4 waves (1/SIMD).
#define SCAN_STEP(WXQ, XQ, KSU, CURB, T)                                       \
  {                                                                            \
    const int nxtb = (CURB) ^ 1;                                               \
    float2 pv = pred[(CURB)][lane & 3];                                        \
    float rn = red4(pv.x), rg = red4(pv.y);                                    \
    const float inv  = rsqrtf(rn);                                             \
    const float gate = __builtin_amdgcn_rcpf(1.f + __expf(-(inv*rg + (KSU)))); \
    if (c15 < 2) {                                                             \
      _Pragma("unroll")                                                        \
      for (int kt = 0; kt < 8; ++kt)                                           \
        a[kt] = *(const bf16x8*)&arr[(CURB)][c15][kt*32 + g*8];                \
    }                                                                          \
    f32x4 q[4][2];                                                             \
    _Pragma("unroll")                                                          \
    for (int tl = 0; tl < 4; ++tl)                                             \
      _Pragma("unroll")                                                        \
      for (int kh = 0; kh < 2; ++kh)                                           \
        q[tl][kh] = (f32x4){0.f, 0.f, 0.f, 0.f};                               \
    _Pragma("unroll")                                                          \
    for (int ki = 0; ki < 4; ++ki) {                                           \
      _Pragma("unroll")                                                        \
      for (int tl = 0; tl < 4; ++tl) {                                         \
        q[tl][0] = __builtin_amdgcn_mfma_f32_16x16x32_bf16(a[ki],     bU[tl][ki],     q[tl][0], 0, 0, 0); \
        q[tl][1] = __builtin_amdgcn_mfma_f32_16x16x32_bf16(a[ki + 4], bU[tl][ki + 4], q[tl][1], 0, 0, 0); \
      }                                                                        \
    }                                                                          \
    if (own) {                                                                 \
      float ns = 0.f, gs = 0.f;                                                \
      _Pragma("unroll")                                                        \
      for (int tau = 0; tau < 4; ++tau) {                                      \
        const float xnt = CSEL(XQ, tau);                                       \
        const float wxt = CSEL(WXQ, tau);                                      \
        float ymm = (q[tau][0][0] + q[tau][1][0])                              \
                  + (q[tau][0][1] + q[tau][1][1]);                             \
        float y  = inv*ymm + kv[tau] + wxt;                                    \
        float hs = (y >= 0.f) ? y : am*y;                                      \
        float hn = inv*h[tau] + gate*hs;                                       \
        h[tau] = hn;                                                           \
        ns += hn*hn;  gs += hn*xnt;                                            \
        ushort hh, hl; split_hilo(hn, hh, hl);                                 \
        int hh2 = dpp_i<0xB1>((int)hh);                                        \
        int hl2 = dpp_i<0xB1>((int)hl);                                        \
        if (evn) {                                                             \
          uint ph = (uint)hh | ((uint)(ushort)hh2 << 16);                      \
          uint pl = (uint)hl | ((uint)(ushort)hl2 << 16);                      \
          const int ucol = 32*w + 8*tau + (c15 >> 1);                          \
          ((uint*)&arr[nxtb][0][0])[ucol] = ph;                                \
          ((uint*)&arr[nxtb][1][0])[ucol] = pl;                                \
        }                                                                      \
      }                                                                        \
      ns = red16(ns);  gs = red16(gs);                                         \
      if (lane == 0) pred[nxtb][w] = make_float2(ns, gs);                      \
    }                                                                          \
    {                                                                          \
      const int tw = ((T) + 4 < N_SENT) ? (T) + 4 : N_SENT - 1;                \
      const int tx = ((T) + 5 < N_SENT) ? (T) + 5 : N_SENT - 1;                \
      if (own) {                                                               \
        WXQ.x = WX[tw*DD + col0]; WXQ.y = WX[tw*DD + col1];                    \
        WXQ.z = WX[tw*DD + col2]; WXQ.w = WX[tw*DD + col3];                    \
        XQ.x  = X [tx*DD + col0]; XQ.y  = X [tx*DD + col1];                    \
        XQ.z  = X [tx*DD + col2]; XQ.w  = X [tx*DD + col3];                    \
      }                                                                        \
      KSU = KS[tw*NB + j];                                                     \
    }                                                                          \
    asm volatile("s_waitcnt lgkmcnt(0)" ::: "memory");                         \
    __builtin_amdgcn_sched_barrier(0);                                         \
    __builtin_amdgcn_s_barrier();                                              \
    __builtin_amdgcn_sched_barrier(0);                                         \
  }

// ---------------- sequential scan: 1 chain/block, 4 waves (1/SIMD) ----------------
// R13 semantics; 4 waves so the per-step barrier syncs half the participants
// and per-SIMD issue is one wave's 32 MFMA + ~160 VALU. B = 128 VGPR/wave
// (waves_per_eu(1,1) -> 512-reg budget, 1 block/CU structurally).
__global__ __launch_bounds__(256)
__attribute__((amdgpu_waves_per_eu(1, 1)))
void scan_kernel(
    const float* __restrict__ X,  const float* __restrict__ WX,
    const float* __restrict__ KS, const float* __restrict__ KVB,
    const ushort* __restrict__ Bf, const float* __restrict__ h0,
    const float* __restrict__ a_mem_p, float* __restrict__ Hf,
    float* __restrict__ HfOut)
{
    const int j    = blockIdx.x;       // chain 0..31
    const int tid  = threadIdx.x;
    const int w    = tid >> 6;         // wave 0..3
    const int lane = tid & 63;
    const int c15  = lane & 15;
    const int g    = lane >> 4;        // 0..3
    const bool own = (g == 0);         // lanes 0-15 own the state
    const bool evn = !(c15 & 1);

    __shared__ __align__(16) ushort arr[2][2][PADC];  // [buf][hi/lo][k]
    __shared__ float2 pred[2][4];                     // [buf][wave] (ns,gs)

    // ---- B fragments [tile][kt] = 32 bf16x8 = 128 regs, persist ----
    bf16x8 bU[4][8];
#pragma unroll
    for (int tl = 0; tl < 4; ++tl)
#pragma unroll
        for (int kt = 0; kt < 8; ++kt)
            bU[tl][kt] = *(const bf16x8*)
                &Bf[(((size_t)(4*w + tl)*8 + kt)*64 + lane)*8];

    const float am = *a_mem_p;
    const int col0 = 64*w + c15,  col1 = col0 + 16;
    const int col2 = col0 + 32,   col3 = col0 + 48;

    // ---- init: state + consts in g==0 lanes; A buf0; pred0 ----
    float h[4] = {0.f,0.f,0.f,0.f}, kv[4] = {0.f,0.f,0.f,0.f};
    float gsi = 0.f;
    if (own) {
#pragma unroll
        for (int tau = 0; tau < 4; ++tau) {
            const int ct = col0 + 16*tau;
            h[tau]  = h0[j*DD + ct];
            kv[tau] = KVB[j*DD + ct];
            gsi += h[tau] * X[ct];
            ushort hh, hl; split_hilo(h[tau], hh, hl);
            arr[0][0][ct] = hh;  arr[0][1][ct] = hl;
        }
        gsi = red16(gsi);
    }
    if (lane == 0) pred[0][w] = make_float2(0.25f, gsi);   // ns sums to 1 -> inv=1

    // ---- prefetch queue sets k=0..3: wx=WX[k], x=X[k+1], ks=KS[k] ----
    float4 wxq0 = {0,0,0,0}, wxq1 = {0,0,0,0}, wxq2 = {0,0,0,0}, wxq3 = {0,0,0,0};
    float4 xq0  = {0,0,0,0}, xq1  = {0,0,0,0}, xq2  = {0,0,0,0}, xq3  = {0,0,0,0};
    if (own) {
        wxq0 = make_float4(WX[col0],       WX[col1],       WX[col2],       WX[col3]);
        wxq1 = make_float4(WX[DD+col0],    WX[DD+col1],    WX[DD+col2],    WX[DD+col3]);
        wxq2 = make_float4(WX[2*DD+col0],  WX[2*DD+col1],  WX[2*DD+col2],  WX[2*DD+col3]);
        wxq3 = make_float4(WX[3*DD+col0],  WX[3*DD+col1],  WX[3*DD+col2],  WX[3*DD+col3]);
        xq0  = make_float4(X[DD+col0],     X[DD+col1],     X[DD+col2],     X[DD+col3]);
        xq1  = make_float4(X[2*DD+col0],   X[2*DD+col1],   X[2*DD+col2],   X[2*DD+col3]);
        xq2  = make_float4(X[3*DD+col0],   X[3*DD+col1],   X[3*DD+col2],   X[3*DD+col3]);
        xq3  = make_float4(X[4*DD+col0],   X[4*DD+col1],   X[4*DD+col2],   X[4*DD+col3]);
    }
    float ks0 = KS[j], ks1 = KS[NB + j], ks2 = KS[2*NB + j], ks3 = KS[3*NB + j];
    __syncthreads();

    bf16x8 a[8];
#pragma unroll
    for (int kt = 0; kt < 8; ++kt) a[kt] = (bf16x8){0,0,0,0,0,0,0,0};

    for (int tb = 0; tb < N_SENT; tb += 4) {
        SCAN_STEP(wxq0, xq0, ks0, 0, tb + 0);
        SCAN_STEP(wxq1, xq1, ks1, 1, tb + 1);
        SCAN_STEP(wxq2, xq2, ks2, 0, tb + 2);
        SCAN_STEP(wxq3, xq3, ks3, 1, tb + 3);
    }

    // ---- final normalize + output (2048 steps -> final buf = 0) ----
    {
        float2 pv = pred[0][lane & 3];
        const float inv = rsqrtf(red4(pv.x));
        if (own) {
#pragma unroll
            for (int tau = 0; tau < 4; ++tau) {
                const int ct = col0 + 16*tau;
                const float v = h[tau] * inv;
                Hf[j*DD + ct]    = v;
                HfOut[j*DD + ct] = v;
            }
        }
    }
}

// ---------------- output module small part ----------------
__global__ __launch_bounds__(256) void out_small(
    const float* __restrict__ Qe, const float* __restrict__ Hfm,
    const float* __restrict__ Hw, const float* __restrict__ Hb,
    const float* __restrict__ a_out_p, float* __restrict__ Z)
{
    const int i = blockIdx.x, d = threadIdx.x;
    __shared__ float hsh[NB*DD];
    __shared__ float red[4];
    __shared__ float csh[NB];
    __shared__ float ush[DD];
#pragma unroll
    for (int jj = 0; jj < NB; ++jj) hsh[jj*DD + d] = Hfm[jj*DD + d];
    const float qd = Qe[i*DD + d];
    __syncthreads();
    float s2 = 0.f;
#pragma unroll
    for (int jj = 0; jj < NB; ++jj) { float h = hsh[jj*DD + d]; s2 += h*h; }
    for (int jj = 0; jj < NB; ++jj) {
        float p = qd * hsh[jj*DD + d];
        float m = p;
#pragma unroll
        for (int o = 32; o; o >>= 1) m = fmaxf(m, __shfl_xor(m, o));
        if ((d & 63) == 0) red[d >> 6] = m;
        __syncthreads();
        m = fmaxf(fmaxf(red[0], red[1]), fmaxf(red[2], red[3]));
        __syncthreads();
        float e = expf(p - m);
#pragma unroll
        for (int o = 32; o; o >>= 1) e += __shfl_xor(e, o);
        if ((d & 63) == 0) red[d >> 6] = e;
        __syncthreads();
        if (d == 0) csh[jj] = m + logf(red[0] + red[1] + red[2] + red[3]);
        __syncthreads();
    }
    float u = qd * s2;
#pragma unroll
    for (int jj = 0; jj < NB; ++jj) u -= csh[jj] * hsh[jj*DD + d];
    ush[d] = u;
    __syncthreads();
    float acc = qd + Hb[d];
    const float4* hwr = (const float4*)&Hw[d*DD];
    const float4* up  = (const float4*)ush;
#pragma unroll 8
    for (int k4 = 0; k4 < 64; ++k4) {
        float4 w = hwr[k4], uu = up[k4];
        acc += w.x*uu.x + w.y*uu.y + w.z*uu.z + w.w*uu.w;
    }
    const float ao = *a_out_p;
    Z[i*DD + d] = (acc >= 0.f) ? acc : ao * acc;
}

// ---------------- big GEMM: Y = Z @ Rw^T + Rb ----------------
__global__ __launch_bounds__(256) void out_gemm(
    const float* __restrict__ Z, const float* __restrict__ Rw,
    const float* __restrict__ Rb, float* __restrict__ Y)
{
    const int vt  = blockIdx.x * 64;
    const int tid = threadIdx.x;
    __shared__ float rw_sh[64*DD];
    __shared__ float z_sh[64*DD];
#pragma unroll
    for (int it = 0; it < 16; ++it) {
        int f = tid + it*256;
        int row = f >> 6, c = f & 63;
        float4 v = *(const float4*)&Rw[(size_t)(vt + row)*DD + 4*c];
        int u = c ^ ((row >> 2) & 7);
        *(float4*)&rw_sh[row*DD + 4*u] = v;
    }
    const int vg = tid & 15;
    const int ig = tid >> 4;
    const float4 rb4 = *(const float4*)&Rb[vt + vg*4];

    for (int ic = 0; ic < 2; ++ic) {
        const int i0 = ic * 64;
        __syncthreads();
#pragma unroll
        for (int it = 0; it < 16; ++it) {
            int f = tid + it*256;
            int row = f >> 6, c = f & 63;
            float4 v = *(const float4*)&Z[(i0 + row)*DD + 4*c];
            int u = c ^ ((row >> 2) & 7);
            *(float4*)&z_sh[row*DD + 4*u] = v;
        }
        __syncthreads();
        float acc[4][4];
#pragma unroll
        for (int b = 0; b < 4; ++b)
#pragma unroll
            for (int a = 0; a < 4; ++a) acc[b][a] = 0.f;
#pragma unroll 2
        for (int kc = 0; kc < 64; ++kc) {
            float4 ra[4], zb[4];
            const int ur = (kc ^ (vg & 7)) * 4;
            const int uz = (kc ^ (ig & 7)) * 4;
#pragma unroll
            for (int a = 0; a < 4; ++a) ra[a] = *(const float4*)&rw_sh[(vg*4 + a)*DD + ur];
#pragma unroll
            for (int b = 0; b < 4; ++b) zb[b] = *(const float4*)&z_sh[(ig*4 + b)*DD + uz];
#pragma unroll
            for (int b = 0; b < 4; ++b)
#pragma unroll
                for (int a = 0; a < 4; ++a)
                    acc[b][a] += zb[b].x*ra[a].x + zb[b].y*ra[a].y
                               + zb[b].z*ra[a].z + zb[b].w*ra[a].w;
        }
#pragma unroll
        for (int b = 0; b < 4; ++b) {
            int i = i0 + ig*4 + b;
            float4 o;
            o.x = acc[b][0] + rb4.x; o.y = acc[b][1] + rb4.y;
            o.z = acc[b][2] + rb4.z; o.w = acc[b][3] + rb4.w;
            *(float4*)&Y[(size_t)i*VOCAB + vt + vg*4] = o;
        }
    }
}

extern "C" void kernel_launch(void* const* d_in, const int* in_sizes, int n_in,
                              void* d_out, int out_size, void* d_ws, size_t ws_size,
                              hipStream_t stream)
{
    (void)in_sizes; (void)n_in; (void)out_size; (void)ws_size;
    const int*   inputs  = (const int*)  d_in[0];
    const int*   query   = (const int*)  d_in[1];
    const float* h0      = (const float*)d_in[2];
    const float* emb     = (const float*)d_in[3];
    const float* f_story = (const float*)d_in[4];
    const float* f_query = (const float*)d_in[5];
    const float* U       = (const float*)d_in[6];
    const float* V       = (const float*)d_in[7];
    const float* W       = (const float*)d_in[8];
    const float* bias    = (const float*)d_in[9];
    const float* keys    = (const float*)d_in[10];
    const float* a_mem   = (const float*)d_in[11];
    const float* Hw      = (const float*)d_in[12];
    const float* Hb      = (const float*)d_in[13];
    const float* Rw      = (const float*)d_in[14];
    const float* Rb      = (const float*)d_in[15];
    const float* a_out   = (const float*)d_in[16];

    float* ws  = (float*)d_ws;
    float* X   = ws + WS_X;
    float* WX  = ws + WS_WX;
    float* Qe  = ws + WS_Q;
    float* KS  = ws + WS_KS;
    float* KVB = ws + WS_KVB;
    float* Hf  = ws + WS_HF;
    float* Z   = ws + WS_Z;
    ushort* Bf = (ushort*)(ws + WS_BF);

    float* Y     = (float*)d_out;
    float* HfOut = Y + (size_t)NQ * VOCAB;

    encode_story<<<N_SENT, 256, 0, stream>>>(inputs, emb, f_story, X);
    encode_query<<<NQ,    256, 0, stream>>>(query,  emb, f_query, Qe);
    wx_ks      <<<N_SENT, 256, 0, stream>>>(X, W, keys, WX, KS);
    kvb_kernel <<<NB,     256, 0, stream>>>(keys, V, bias, KVB);
    prep_ufrag <<<128,     64, 0, stream>>>(U, Bf);
    scan_kernel<<<NB,     256, 0, stream>>>(X, WX, KS, KVB, Bf, h0, a_mem, Hf, HfOut);
    out_small  <<<NQ,     256, 0, stream>>>(Qe, Hf, Hw, Hb, a_out, Z);
    out_gemm   <<<VOCAB/64, 256, 0, stream>>>(Z, Rw, Rb, Y);
}

// Round 16
// 1819.690 us; speedup vs baseline: 1.1950x; 1.1950x over previous
//
#include <hip/hip_runtime.h>
#include <hip/hip_bf16.h>

#define N_SENT 2048
#define S_LEN  64
#define QL     16
#define NQ     128
#define NB     32
#define DD     256
#define VOCAB  100032

#define PADC 264        // A row length (ushort), 528B = 16B-aligned rows

using bf16x8 = __attribute__((ext_vector_type(8))) short;
using f32x4  = __attribute__((ext_vector_type(4))) float;

// ---------------- workspace layout (float offsets) ----------------
#define WS_X   0
#define WS_WX  (WS_X  + N_SENT*DD)
#define WS_Q   (WS_WX + N_SENT*DD)
#define WS_KS  (WS_Q  + NQ*DD)
#define WS_KVB (WS_KS + N_SENT*NB)
#define WS_HF  (WS_KVB+ NB*DD)
#define WS_Z   (WS_HF + NB*DD)
#define WS_BF  (WS_Z  + NQ*DD)        // 65536 ushort (single-pass U_rne frags)

// ---------------- encoders ----------------
__global__ __launch_bounds__(256) void encode_story(
    const int* __restrict__ inp, const float* __restrict__ emb,
    const float* __restrict__ f, float* __restrict__ X)
{
    const int t = blockIdx.x, d = threadIdx.x;
    __shared__ int idx[S_LEN];
    if (d < S_LEN) idx[d] = inp[t*S_LEN + d];
    __syncthreads();
    float acc = 0.f;
#pragma unroll 4
    for (int p = 0; p < S_LEN; ++p)
        acc += emb[(size_t)idx[p]*DD + d] * f[p*DD + d];
    X[t*DD + d] = acc;
}

__global__ __launch_bounds__(256) void encode_query(
    const int* __restrict__ qry, const float* __restrict__ emb,
    const float* __restrict__ f, float* __restrict__ Q)
{
    const int i = blockIdx.x, d = threadIdx.x;
    __shared__ int idx[QL];
    if (d < QL) idx[d] = qry[i*QL + d];
    __syncthreads();
    float acc = 0.f;
#pragma unroll
    for (int p = 0; p < QL; ++p)
        acc += emb[(size_t)idx[p]*DD + d] * f[p*DD + d];
    Q[i*DD + d] = acc;
}

// ---------------- WX / KS ----------------
__global__ __launch_bounds__(256) void wx_ks(
    const float* __restrict__ X, const float* __restrict__ W,
    const float* __restrict__ keys, float* __restrict__ WX, float* __restrict__ KS)
{
    const int t = blockIdx.x, n = threadIdx.x;
    __shared__ float xs[DD];
    xs[n] = X[t*DD + n];
    __syncthreads();
    float acc = 0.f;
    const float4* wr = (const float4*)&W[n*DD];
    const float4* xp = (const float4*)xs;
#pragma unroll 8
    for (int k4 = 0; k4 < 64; ++k4) {
        float4 w = wr[k4], x = xp[k4];
        acc += w.x*x.x + w.y*x.y + w.z*x.z + w.w*x.w;
    }
    WX[t*DD + n] = acc;
    if (n < NB) {
        float a2 = 0.f;
        const float4* kr = (const float4*)&keys[n*DD];
#pragma unroll 8
        for (int k4 = 0; k4 < 64; ++k4) {
            float4 kv = kr[k4], x = xp[k4];
            a2 += kv.x*x.x + kv.y*x.y + kv.z*x.z + kv.w*x.w;
        }
        KS[t*NB + n] = a2;
    }
}

// ---------------- KVB ----------------
__global__ __launch_bounds__(256) void kvb_kernel(
    const float* __restrict__ keys, const float* __restrict__ V,
    const float* __restrict__ bias, float* __restrict__ KVB)
{
    const int jj = blockIdx.x, n = threadIdx.x;
    __shared__ float ks[DD];
    ks[n] = keys[jj*DD + n];
    __syncthreads();
    float acc = bias[n];
    const float4* vr = (const float4*)&V[n*DD];
    const float4* kp = (const float4*)ks;
#pragma unroll 8
    for (int k4 = 0; k4 < 64; ++k4) {
        float4 v = vr[k4], k = kp[k4];
        acc += v.x*k.x + v.y*k.y + v.z*k.z + v.w*k.w;
    }
    KVB[jj*DD + n] = acc;
}

// ---------------- prep: U -> RNE bf16 MFMA B-fragments (single pass) ----------------
// frag f = ntile*8 + ktile; lane l: B[k][n] = U_rne[n][k],
// n = ntile*16 + (l&15), k = ktile*32 + (l>>4)*8 + i.  RNE halves |dU|.
__global__ __launch_bounds__(64) void prep_ufrag(
    const float* __restrict__ U, ushort* __restrict__ Bf)
{
    const int f = blockIdx.x;         // 0..127
    const int l = threadIdx.x;        // 0..63
    const int kt = f & 7, nt = f >> 3;
    const int n  = nt*16 + (l & 15);
    const int kb = kt*32 + (l >> 4)*8;
    ushort out[8];
#pragma unroll
    for (int i = 0; i < 8; ++i) {
        __hip_bfloat16 b = __float2bfloat16(U[n*DD + kb + i]);  // RNE
        out[i] = *reinterpret_cast<ushort*>(&b);
    }
    *(uint4*)&Bf[((size_t)f*64 + l)*8] = *(const uint4*)out;
}

__device__ __forceinline__ void split_hilo(float v, ushort& hi, ushort& lo)
{
    unsigned b = __float_as_uint(v);
    unsigned h = b & 0xFFFF0000u;
    hi = (ushort)(h >> 16);
    lo = (ushort)(__float_as_uint(v - __uint_as_float(h)) >> 16);
}

template <int CTRL>
__device__ __forceinline__ int dpp_i(int v) {
    return __builtin_amdgcn_update_dpp(0, v, CTRL, 0xF, 0xF, true);
}
template <int CTRL>
__device__ __forceinline__ float dpp_f(float x) {
    return __int_as_float(dpp_i<CTRL>(__float_as_int(x)));
}

__device__ __forceinline__ float red16(float x) {   // sum over 16-lane row
    x += dpp_f<0xB1>(x);
    x += dpp_f<0x4E>(x);
    x += dpp_f<0x141>(x);
    x += dpp_f<0x140>(x);
    return x;
}
__device__ __forceinline__ float red8(float x) {    // sum over 8-lane group
    x += dpp_f<0xB1>(x);
    x += dpp_f<0x4E>(x);
    x += dpp_f<0x141>(x);
    return x;
}

// One scan step. A rows {0:hhi, 1:hlo}; single B pass (U_rne):
// y = D.row0 + D.row1 = (hhi+hlo)*U_rne = h*U_rne (exact in h; error h*dU).
#define SCAN_STEP(WXU0, WXU1, XU0, XU1, KSU, CURB, T)                          \
  {                                                                            \
    const int nxtb = (CURB) ^ 1;                                               \
    float2 pv = pred[(CURB)][lane & 7];                                        \
    float rn = red8(pv.x), rg = red8(pv.y);                                    \
    const float inv  = rsqrtf(rn);                                             \
    const float gate = __builtin_amdgcn_rcpf(1.f + __expf(-(inv*rg + (KSU)))); \
    if (c15 < 2) {                                                             \
      _Pragma("unroll")                                                        \
      for (int kt = 0; kt < 8; ++kt)                                           \
        a[kt] = *(const bf16x8*)&arr[(CURB)][c15][kt*32 + g*8];                \
    }                                                                          \
    f32x4 q[2][2];                                                             \
    _Pragma("unroll")                                                          \
    for (int tau = 0; tau < 2; ++tau)                                          \
      _Pragma("unroll")                                                        \
      for (int kh = 0; kh < 2; ++kh)                                           \
        q[tau][kh] = (f32x4){0.f, 0.f, 0.f, 0.f};                              \
    _Pragma("unroll")                                                          \
    for (int ki = 0; ki < 4; ++ki) {                                           \
      q[0][0] = __builtin_amdgcn_mfma_f32_16x16x32_bf16(a[ki],     bU[0][ki],     q[0][0], 0, 0, 0); \
      q[1][0] = __builtin_amdgcn_mfma_f32_16x16x32_bf16(a[ki],     bU[1][ki],     q[1][0], 0, 0, 0); \
      q[0][1] = __builtin_amdgcn_mfma_f32_16x16x32_bf16(a[ki + 4], bU[0][ki + 4], q[0][1], 0, 0, 0); \
      q[1][1] = __builtin_amdgcn_mfma_f32_16x16x32_bf16(a[ki + 4], bU[1][ki + 4], q[1][1], 0, 0, 0); \
    }                                                                          \
    if (own) {                                                                 \
      float ns = 0.f, gs = 0.f;                                                \
      _Pragma("unroll")                                                        \
      for (int tau = 0; tau < 2; ++tau) {                                      \
        const float xnt = tau ? (XU1) : (XU0);                                 \
        const float wxt = tau ? (WXU1) : (WXU0);                               \
        float ymm = (q[tau][0][0] + q[tau][1][0])                              \
                  + (q[tau][0][1] + q[tau][1][1]);                             \
        float y  = inv*ymm + kv[tau] + wxt;                                    \
        float hs = (y >= 0.f) ? y : am*y;                                      \
        float hn = inv*h[tau] + gate*hs;                                       \
        h[tau] = hn;                                                           \
        ns += hn*hn;  gs += hn*xnt;                                            \
        ushort hh, hl; split_hilo(hn, hh, hl);                                 \
        int hh2 = dpp_i<0xB1>((int)hh);                                        \
        int hl2 = dpp_i<0xB1>((int)hl);                                        \
        if (evn) {                                                             \
          uint ph = (uint)hh | ((uint)(ushort)hh2 << 16);                      \
          uint pl = (uint)hl | ((uint)(ushort)hl2 << 16);                      \
          const int ucol = 16*w + 8*tau + (c15 >> 1);                          \
          ((uint*)&arr[nxtb][0][0])[ucol] = ph;                                \
          ((uint*)&arr[nxtb][1][0])[ucol] = pl;                                \
        }                                                                      \
      }                                                                        \
      ns = red16(ns);  gs = red16(gs);                                         \
      if (lane == 0) pred[nxtb][w] = make_float2(ns, gs);                      \
    }                                                                          \
    {                                                                          \
      const int tw = ((T) + 4 < N_SENT) ? (T) + 4 : N_SENT - 1;                \
      const int tx = ((T) + 5 < N_SENT) ? (T) + 5 : N_SENT - 1;                \
      if (own) {                                                               \
        WXU0 = WX[tw*DD + col0];  WXU1 = WX[tw*DD + col1];                     \
        XU0  = X [tx*DD + col0];  XU1  = X [tx*DD + col1];                     \
      }                                                                        \
      KSU = KS[tw*NB + j];                                                     \
    }                                                                          \
    asm volatile("s_waitcnt lgkmcnt(0)" ::: "memory");                         \
    __builtin_amdgcn_sched_barrier(0);                                         \
    __builtin_amdgcn_s_barrier();                                              \
    __builtin_amdgcn_sched_barrier(0);                                         \
  }

// ---------------- sequential scan: 1 chain/block, single-pass U ----------------
// Best-known configuration (R13): M=2 hi/lo rows, 8 waves (2/SIMD), one
// exchange + raw barrier per step, 4-set deep prefetch, single-pass RNE-bf16
// U (16 MFMAs/wave).
__global__ __launch_bounds__(512)
__attribute__((amdgpu_waves_per_eu(2, 2)))
void scan_kernel(
    const float* __restrict__ X,  const float* __restrict__ WX,
    const float* __restrict__ KS, const float* __restrict__ KVB,
    const ushort* __restrict__ Bf, const float* __restrict__ h0,
    const float* __restrict__ a_mem_p, float* __restrict__ Hf,
    float* __restrict__ HfOut)
{
    const int j    = blockIdx.x;       // chain 0..31
    const int tid  = threadIdx.x;
    const int w    = tid >> 6;         // wave 0..7
    const int lane = tid & 63;
    const int c15  = lane & 15;
    const int g    = lane >> 4;        // 0..3
    const bool own = (g == 0);         // lanes 0-15 own the state
    const bool evn = !(c15 & 1);

    __shared__ __align__(16) ushort arr[2][2][PADC];  // [buf][hi/lo][k]
    __shared__ float2 pred[2][8];                     // [buf][wave] (ns,gs)

    // ---- B fragments [tile][kt] = 16 bf16x8 = 64 regs, persist ----
    bf16x8 bU[2][8];
#pragma unroll
    for (int tau = 0; tau < 2; ++tau)
#pragma unroll
        for (int kt = 0; kt < 8; ++kt)
            bU[tau][kt] = *(const bf16x8*)
                &Bf[(((size_t)(2*w + tau)*8 + kt)*64 + lane)*8];

    const float am = *a_mem_p;
    const int col0 = 32*w + c15, col1 = col0 + 16;

    // ---- init: state + consts in g==0 lanes; A buf0; pred0 ----
    float h[2] = {0.f, 0.f}, kv[2] = {0.f, 0.f};
    float gsi = 0.f;
    if (own) {
#pragma unroll
        for (int tau = 0; tau < 2; ++tau) {
            const int ct = tau ? col1 : col0;
            h[tau]  = h0[j*DD + ct];
            kv[tau] = KVB[j*DD + ct];
            gsi += h[tau] * X[ct];
            ushort hh, hl; split_hilo(h[tau], hh, hl);
            arr[0][0][ct] = hh;  arr[0][1][ct] = hl;
        }
        gsi = red16(gsi);
    }
    if (lane == 0) pred[0][w] = make_float2(0.125f, gsi);  // ns sums to 1 -> inv=1

    // ---- prefetch queue sets k=0..3: wx=WX[k], x=X[k+1], ks=KS[k] ----
    float wx00=0,wx01=0,x00=0,x01=0, wx10=0,wx11=0,x10=0,x11=0;
    float wx20=0,wx21=0,x20=0,x21=0, wx30=0,wx31=0,x30=0,x31=0;
    if (own) {
        wx00 = WX[       col0]; wx01 = WX[       col1];
        wx10 = WX[  DD + col0]; wx11 = WX[  DD + col1];
        wx20 = WX[2*DD + col0]; wx21 = WX[2*DD + col1];
        wx30 = WX[3*DD + col0]; wx31 = WX[3*DD + col1];
        x00  = X [  DD + col0]; x01  = X [  DD + col1];
        x10  = X [2*DD + col0]; x11  = X [2*DD + col1];
        x20  = X [3*DD + col0]; x21  = X [3*DD + col1];
        x30  = X [4*DD + col0]; x31  = X [4*DD + col1];
    }
    float ks0 = KS[j], ks1 = KS[NB + j], ks2 = KS[2*NB + j], ks3 = KS[3*NB + j];
    __syncthreads();

    bf16x8 a[8];
#pragma unroll
    for (int kt = 0; kt < 8; ++kt) a[kt] = (bf16x8){0,0,0,0,0,0,0,0};

    for (int tb = 0; tb < N_SENT; tb += 4) {
        SCAN_STEP(wx00, wx01, x00, x01, ks0, 0, tb + 0);
        SCAN_STEP(wx10, wx11, x10, x11, ks1, 1, tb + 1);
        SCAN_STEP(wx20, wx21, x20, x21, ks2, 0, tb + 2);
        SCAN_STEP(wx30, wx31, x30, x31, ks3, 1, tb + 3);
    }

    // ---- final normalize + output (2048 steps -> final buf = 0) ----
    {
        float2 pv = pred[0][lane & 7];
        const float inv = rsqrtf(red8(pv.x));
        if (own) {
#pragma unroll
            for (int tau = 0; tau < 2; ++tau) {
                const int ct = tau ? col1 : col0;
                const float v = h[tau] * inv;
                Hf[j*DD + ct]    = v;
                HfOut[j*DD + ct] = v;
            }
        }
    }
}

// ---------------- output module small part ----------------
__global__ __launch_bounds__(256) void out_small(
    const float* __restrict__ Qe, const float* __restrict__ Hfm,
    const float* __restrict__ Hw, const float* __restrict__ Hb,
    const float* __restrict__ a_out_p, float* __restrict__ Z)
{
    const int i = blockIdx.x, d = threadIdx.x;
    __shared__ float hsh[NB*DD];
    __shared__ float red[4];
    __shared__ float csh[NB];
    __shared__ float ush[DD];
#pragma unroll
    for (int jj = 0; jj < NB; ++jj) hsh[jj*DD + d] = Hfm[jj*DD + d];
    const float qd = Qe[i*DD + d];
    __syncthreads();
    float s2 = 0.f;
#pragma unroll
    for (int jj = 0; jj < NB; ++jj) { float h = hsh[jj*DD + d]; s2 += h*h; }
    for (int jj = 0; jj < NB; ++jj) {
        float p = qd * hsh[jj*DD + d];
        float m = p;
#pragma unroll
        for (int o = 32; o; o >>= 1) m = fmaxf(m, __shfl_xor(m, o));
        if ((d & 63) == 0) red[d >> 6] = m;
        __syncthreads();
        m = fmaxf(fmaxf(red[0], red[1]), fmaxf(red[2], red[3]));
        __syncthreads();
        float e = expf(p - m);
#pragma unroll
        for (int o = 32; o; o >>= 1) e += __shfl_xor(e, o);
        if ((d & 63) == 0) red[d >> 6] = e;
        __syncthreads();
        if (d == 0) csh[jj] = m + logf(red[0] + red[1] + red[2] + red[3]);
        __syncthreads();
    }
    float u = qd * s2;
#pragma unroll
    for (int jj = 0; jj < NB; ++jj) u -= csh[jj] * hsh[jj*DD + d];
    ush[d] = u;
    __syncthreads();
    float acc = qd + Hb[d];
    const float4* hwr = (const float4*)&Hw[d*DD];
    const float4* up  = (const float4*)ush;
#pragma unroll 8
    for (int k4 = 0; k4 < 64; ++k4) {
        float4 w = hwr[k4], uu = up[k4];
        acc += w.x*uu.x + w.y*uu.y + w.z*uu.z + w.w*uu.w;
    }
    const float ao = *a_out_p;
    Z[i*DD + d] = (acc >= 0.f) ? acc : ao * acc;
}

// ---------------- big GEMM: Y = Z @ Rw^T + Rb ----------------
__global__ __launch_bounds__(256) void out_gemm(
    const float* __restrict__ Z, const float* __restrict__ Rw,
    const float* __restrict__ Rb, float* __restrict__ Y)
{
    const int vt  = blockIdx.x * 64;
    const int tid = threadIdx.x;
    __shared__ float rw_sh[64*DD];
    __shared__ float z_sh[64*DD];
#pragma unroll
    for (int it = 0; it < 16; ++it) {
        int f = tid + it*256;
        int row = f >> 6, c = f & 63;
        float4 v = *(const float4*)&Rw[(size_t)(vt + row)*DD + 4*c];
        int u = c ^ ((row >> 2) & 7);
        *(float4*)&rw_sh[row*DD + 4*u] = v;
    }
    const int vg = tid & 15;
    const int ig = tid >> 4;
    const float4 rb4 = *(const float4*)&Rb[vt + vg*4];

    for (int ic = 0; ic < 2; ++ic) {
        const int i0 = ic * 64;
        __syncthreads();
#pragma unroll
        for (int it = 0; it < 16; ++it) {
            int f = tid + it*256;
            int row = f >> 6, c = f & 63;
            float4 v = *(const float4*)&Z[(i0 + row)*DD + 4*c];
            int u = c ^ ((row >> 2) & 7);
            *(float4*)&z_sh[row*DD + 4*u] = v;
        }
        __syncthreads();
        float acc[4][4];
#pragma unroll
        for (int b = 0; b < 4; ++b)
#pragma unroll
            for (int a = 0; a < 4; ++a) acc[b][a] = 0.f;
#pragma unroll 2
        for (int kc = 0; kc < 64; ++kc) {
            float4 ra[4], zb[4];
            const int ur = (kc ^ (vg & 7)) * 4;
            const int uz = (kc ^ (ig & 7)) * 4;
#pragma unroll
            for (int a = 0; a < 4; ++a) ra[a] = *(const float4*)&rw_sh[(vg*4 + a)*DD + ur];
#pragma unroll
            for (int b = 0; b < 4; ++b) zb[b] = *(const float4*)&z_sh[(ig*4 + b)*DD + uz];
#pragma unroll
            for (int b = 0; b < 4; ++b)
#pragma unroll
                for (int a = 0; a < 4; ++a)
                    acc[b][a] += zb[b].x*ra[a].x + zb[b].y*ra[a].y
                               + zb[b].z*ra[a].z + zb[b].w*ra[a].w;
        }
#pragma unroll
        for (int b = 0; b < 4; ++b) {
            int i = i0 + ig*4 + b;
            float4 o;
            o.x = acc[b][0] + rb4.x; o.y = acc[b][1] + rb4.y;
            o.z = acc[b][2] + rb4.z; o.w = acc[b][3] + rb4.w;
            *(float4*)&Y[(size_t)i*VOCAB + vt + vg*4] = o;
        }
    }
}

extern "C" void kernel_launch(void* const* d_in, const int* in_sizes, int n_in,
                              void* d_out, int out_size, void* d_ws, size_t ws_size,
                              hipStream_t stream)
{
    (void)in_sizes; (void)n_in; (void)out_size; (void)ws_size;
    const int*   inputs  = (const int*)  d_in[0];
    const int*   query   = (const int*)  d_in[1];
    const float* h0      = (const float*)d_in[2];
    const float* emb     = (const float*)d_in[3];
    const float* f_story = (const float*)d_in[4];
    const float* f_query = (const float*)d_in[5];
    const float* U       = (const float*)d_in[6];
    const float* V       = (const float*)d_in[7];
    const float* W       = (const float*)d_in[8];
    const float* bias    = (const float*)d_in[9];
    const float* keys    = (const float*)d_in[10];
    const float* a_mem   = (const float*)d_in[11];
    const float* Hw      = (const float*)d_in[12];
    const float* Hb      = (const float*)d_in[13];
    const float* Rw      = (const float*)d_in[14];
    const float* Rb      = (const float*)d_in[15];
    const float* a_out   = (const float*)d_in[16];

    float* ws  = (float*)d_ws;
    float* X   = ws + WS_X;
    float* WX  = ws + WS_WX;
    float* Qe  = ws + WS_Q;
    float* KS  = ws + WS_KS;
    float* KVB = ws + WS_KVB;
    float* Hf  = ws + WS_HF;
    float* Z   = ws + WS_Z;
    ushort* Bf = (ushort*)(ws + WS_BF);

    float* Y     = (float*)d_out;
    float* HfOut = Y + (size_t)NQ * VOCAB;

    encode_story<<<N_SENT, 256, 0, stream>>>(inputs, emb, f_story, X);
    encode_query<<<NQ,    256, 0, stream>>>(query,  emb, f_query, Qe);
    wx_ks      <<<N_SENT, 256, 0, stream>>>(X, W, keys, WX, KS);
    kvb_kernel <<<NB,     256, 0, stream>>>(keys, V, bias, KVB);
    prep_ufrag <<<128,     64, 0, stream>>>(U, Bf);
    scan_kernel<<<NB,     512, 0, stream>>>(X, WX, KS, KVB, Bf, h0, a_mem, Hf, HfOut);
    out_small  <<<NQ,     256, 0, stream>>>(Qe, Hf, Hw, Hb, a_out, Z);
    out_gemm   <<<VOCAB/64, 256, 0, stream>>>(Z, Rw, Rb, Y);
}